// Round 13
// baseline (132.388 us; speedup 1.0000x reference)
//
#include <hip/hip_runtime.h>
#include <hip/hip_bf16.h>

#define B_N     2048
#define IN_N    512
#define SEQ_N   128
#define HID_N   12
#define HP_N    16
#define OUT_N   3

typedef __attribute__((ext_vector_type(8))) short short8;
typedef __attribute__((ext_vector_type(4))) float f32x4;
typedef __attribute__((ext_vector_type(4))) _Float16 f16x4;
typedef __attribute__((ext_vector_type(8))) _Float16 f16x8;
typedef unsigned int uint;
typedef unsigned short ushort;

__device__ __forceinline__ float fast_tanh(float x) {
    float e = __builtin_amdgcn_exp2f(x * 2.8853900817779268f);
    return 1.0f - 2.0f * __builtin_amdgcn_rcpf(e + 1.0f);
}

// tanh with the 1/ln2*2 scale already folded into the input
__device__ __forceinline__ float tanh_ps(float x) {
    float e = __builtin_amdgcn_exp2f(x);
    return 1.0f - 2.0f * __builtin_amdgcn_rcpf(e + 1.0f);
}

__device__ __forceinline__ ushort f2bf(float f) {   // RNE fp32->bf16
    uint u = __float_as_uint(f);
    u += 0x7fffu + ((u >> 16) & 1u);
    return (ushort)(u >> 16);
}

__device__ __forceinline__ float bf2f(ushort s) {
    return __uint_as_float(((uint)s) << 16);
}

// ---------------------------------------------------------------------------
// Prep: emb (512x128 f32) -> embB F16 (RNE);
// wP = real-mfma B-frags of w_ih_f / w_ih_r at K=16 granularity:
//   wP[istep 0..31][src 0,1][l 0..63][j 0..3] =
//     (h=l&15 < 12) ? f16(w_src[h][i = istep*16 + (l>>4)*4 + j]) : 0
// ---------------------------------------------------------------------------
__global__ __launch_bounds__(256) void k_prep(
    const float* __restrict__ emb, const float* __restrict__ w_ih_f,
    const float* __restrict__ w_ih_r,
    ushort* __restrict__ embB, ushort* __restrict__ wP)
{
    int tid = blockIdx.x * 256 + threadIdx.x;      // 0..16383
    float4 e = ((const float4*)emb)[tid];
    f16x4 hv = {(_Float16)e.x, (_Float16)e.y, (_Float16)e.z, (_Float16)e.w};
    ((f16x4*)embB)[tid] = hv;

    int j     = tid & 3;
    int l     = (tid >> 2) & 63;
    int src   = (tid >> 8) & 1;
    int istep = tid >> 9;                          // 0..31
    int h     = l & 15;
    int i     = istep * 16 + (l >> 4) * 4 + j;
    const float* ws = src ? w_ih_r : w_ih_f;
    _Float16 v = (h < HID_N) ? (_Float16)ws[h * IN_N + i] : (_Float16)0.f;
    ((_Float16*)wP)[((size_t)(istep * 2 + src) * 64 + l) * 4 + j] = v;
}

// ---------------------------------------------------------------------------
// k_pre v6: MFMA-transpose dataflow — NO LDS round-trip for A, NO barriers
// in the main loop.  One wave = one b (4 waves/block, 512 blocks).
//
// Per i-chunk (16 rows): gather 16 rows coalesced (4x dwordx4, full 64B
// lines: lane16=row, quad=16B s-window) -> data lands directly in the
// 16x16x32_f16 A-frag layout (row=lane16, k=quad*8+j).  Transpose via
// mfma(A=E, B=identity): D = E with lane roles swapped (col=s=lane16,
// row=i=quad*4+r) — exact (f16*1.0+0 -> f32 -> f16 cast back, lossless
// since the values are f16-representable).  The converted D IS the
// 16x16x16_f16 A-frag (row=lane16=s, k=quad*4+j=i) for the real GEMM step
// acc[sc] += mfma(E^T_chunk, W-frag).  All lane layouts used here are
// HW-verified this session (k_pre R0-R5, k_rnn v4 bit-identical).
// 3-deep gather pipeline; weights+indices in LDS (40KB, one barrier total).
// rev folded: accR += mfma(a2[sc=7], wR) per i-chunk.
// ---------------------------------------------------------------------------
__global__ __launch_bounds__(256, 2) void k_pre(
    const int* __restrict__ x, const ushort* __restrict__ embB,
    const ushort* __restrict__ wP,
    const float* __restrict__ b_ih_r, const float* __restrict__ b_hh_r,
    ushort* __restrict__ preB, float* __restrict__ rev)
{
    __shared__ __align__(16) ushort wPs[16384];   // 32 KB f16 weight frags
    __shared__ int xbs[4][IN_N];                  // 8 KB indices (per wave)

    const int t      = threadIdx.x;
    const int l      = t & 63;
    const int wv     = t >> 6;
    const int lane16 = l & 15;
    const int quad   = l >> 4;
    const int b      = blockIdx.x * 4 + wv;

    // stage weight frags (cooperative) + this wave's 512 indices
    {
        const uint4* s4 = (const uint4*)wP;
        uint4*       d4 = (uint4*)wPs;
        #pragma unroll
        for (int i = 0; i < 8; ++i) d4[t + i * 256] = s4[t + i * 256];
        const int4* xs = (const int4*)(x + (size_t)b * IN_N);
        ((int4*)xbs[wv])[l]      = xs[l];
        ((int4*)xbs[wv])[l + 64] = xs[l + 64];
    }
    __syncthreads();

    // identity B-frags for transpose-mfma (16x16x32 f16):
    // I1[k][n] = (k==n), I2[k][n] = (k==n+16);  lane: k=quad*8+j, n=lane16
    f16x8 I1, I2;
    #pragma unroll
    for (int j = 0; j < 8; ++j) {
        int k = quad * 8 + j;
        I1[j] = (k == lane16)      ? (_Float16)1.f : (_Float16)0.f;
        I2[j] = (k == lane16 + 16) ? (_Float16)1.f : (_Float16)0.f;
    }

    f32x4 acc[8];
    #pragma unroll
    for (int sc = 0; sc < 8; ++sc) acc[sc] = (f32x4){0.f, 0.f, 0.f, 0.f};
    f32x4 accR = {0.f, 0.f, 0.f, 0.f};
    const f32x4 zz = {0.f, 0.f, 0.f, 0.f};

    uint4 G[3][4];

    // prologue: gather i-chunks 0..2 (3-deep)
    #pragma unroll
    for (int ic = 0; ic < 3; ++ic) {
        int row = xbs[wv][ic * 16 + lane16];
        const ushort* rp = embB + (size_t)row * SEQ_N + quad * 8;
        #pragma unroll
        for (int w = 0; w < 4; ++w) G[ic][w] = *(const uint4*)(rp + w * 32);
    }

    // weight frags for ic 0 (fwd + rev)
    f16x4 bwC = *(const f16x4*)&wPs[0 * 64 * 4 + l * 4];
    f16x4 brC = *(const f16x4*)&wPs[1 * 64 * 4 + l * 4];

    #pragma unroll
    for (int ic = 0; ic < 32; ++ic) {
        // idx for gather(ic+3) — LDS read, latency hidden under this body
        int nrow = 0;
        if (ic + 3 < 32) nrow = xbs[wv][(ic + 3) * 16 + lane16];
        // weight frags for ic+1 (LDS, prefetched one chunk ahead)
        f16x4 bwN = bwC, brN = brC;
        if (ic + 1 < 32) {
            bwN = *(const f16x4*)&wPs[(size_t)(((ic + 1) * 2 + 0) * 64 + l) * 4];
            brN = *(const f16x4*)&wPs[(size_t)(((ic + 1) * 2 + 1) * 64 + l) * 4];
        }

        #pragma unroll
        for (int w = 0; w < 4; ++w) {
            f16x8 Af = *(f16x8*)&G[ic % 3][w];
            // transpose: D1 = E[:, w*32 .. +16], D2 = E[:, w*32+16 .. +32]
            f32x4 d1 = __builtin_amdgcn_mfma_f32_16x16x32_f16(Af, I1, zz, 0, 0, 0);
            f32x4 d2 = __builtin_amdgcn_mfma_f32_16x16x32_f16(Af, I2, zz, 0, 0, 0);
            // exact repack f32->f16 (values are f16-representable)
            f16x4 a1 = {(_Float16)d1[0], (_Float16)d1[1],
                        (_Float16)d1[2], (_Float16)d1[3]};
            f16x4 a2 = {(_Float16)d2[0], (_Float16)d2[1],
                        (_Float16)d2[2], (_Float16)d2[3]};
            // real GEMM step: acc[sc] += E^T_chunk . W   (K = 16 i)
            acc[2 * w]     = __builtin_amdgcn_mfma_f32_16x16x16f16(a1, bwC, acc[2 * w],     0, 0, 0);
            acc[2 * w + 1] = __builtin_amdgcn_mfma_f32_16x16x16f16(a2, bwC, acc[2 * w + 1], 0, 0, 0);
            if (w == 3)   // rev needs only s=127, which lives in sc=7
                accR = __builtin_amdgcn_mfma_f32_16x16x16f16(a2, brC, accR, 0, 0, 0);
        }

        // issue gather(ic+3) into the buffer just consumed
        if (ic + 3 < 32) {
            const ushort* rp = embB + (size_t)nrow * SEQ_N + quad * 8;
            #pragma unroll
            for (int w = 0; w < 4; ++w) G[ic % 3][w] = *(const uint4*)(rp + w * 32);
        }
        bwC = bwN; brC = brN;
    }

    // epilogue: D'[s][h]: lane holds col h = lane16, row s-local = quad*4+r
    if (lane16 < HID_N) {
        #pragma unroll
        for (int sc = 0; sc < 8; ++sc) {
            #pragma unroll
            for (int r = 0; r < 4; ++r)
                preB[((size_t)b * SEQ_N + sc * 16 + quad * 4 + r) * HP_N + lane16] =
                    f2bf(acc[sc][r]);
        }
        // s=127 = sc 7, quad 3, r 3
        if (quad == 3)
            rev[b * HP_N + lane16] =
                fast_tanh(accR[3] + b_ih_r[lane16] + b_hh_r[lane16]);
    }
}

// ---------------------------------------------------------------------------
// k_rnn v4 (EXACT revert to R10 config — measured 18.7 us, best variant):
// self-feeding mfma_f32_16x16x16_f16 recurrence, 32 blocks x 256 thr.
// v5 (64-thr, named regs) measured 23.0 — reverted.
// ---------------------------------------------------------------------------
__global__ __launch_bounds__(256) void k_rnn(
    const ushort* __restrict__ preB, const float* __restrict__ rev,
    const float* __restrict__ w_hh_f,
    const float* __restrict__ b_ih_f, const float* __restrict__ b_hh_f,
    const float* __restrict__ fc_w, const float* __restrict__ fc_b,
    float* __restrict__ out)
{
    __shared__ float ho[64][16];

    const int t      = threadIdx.x;
    const int l      = t & 63;
    const int wv     = t >> 6;            // wave 0..3
    const int lane16 = l & 15;            // column = b
    const int quad   = l >> 4;            // row/k group
    const int bloc   = wv * 16 + lane16;  // b within block (0..63)
    const int b      = blockIdx.x * 64 + bloc;

    const float SC = 2.8853900817779268f;

    // A fragment: A[row=lane16][k=quad*4+j] = SC * W[row][k], zero-padded
    f16x4 aW;
    {
        float w0_=0.f, w1_=0.f, w2_=0.f, w3_=0.f;
        if (lane16 < HID_N && quad < 3) {
            const float* wr = w_hh_f + lane16 * 12 + quad * 4;
            w0_ = wr[0]; w1_ = wr[1]; w2_ = wr[2]; w3_ = wr[3];
        }
        aW[0] = (_Float16)(SC * w0_);
        aW[1] = (_Float16)(SC * w1_);
        aW[2] = (_Float16)(SC * w2_);
        aW[3] = (_Float16)(SC * w3_);
    }

    // bias (pre-scaled); zero for pad rows (quad 3)
    float bias0=0.f, bias1=0.f, bias2=0.f, bias3=0.f;
    if (quad < 3) {
        const int h = quad * 4;
        bias0 = SC * (b_ih_f[h]     + b_hh_f[h]);
        bias1 = SC * (b_ih_f[h + 1] + b_hh_f[h + 1]);
        bias2 = SC * (b_ih_f[h + 2] + b_hh_f[h + 2]);
        bias3 = SC * (b_ih_f[h + 3] + b_hh_f[h + 3]);
    }

    // p prefetch, 16 deep: 4 bf16 (h=quad*4..+3) per step
    const ushort* pb = preB + (size_t)b * SEQ_N * HP_N + quad * 4;
    uint2 pq[16];
    #pragma unroll
    for (int k = 0; k < 16; ++k) pq[k] = *(const uint2*)(pb + k * HP_N);

    f16x4 hB = {(_Float16)0.f, (_Float16)0.f, (_Float16)0.f, (_Float16)0.f};
    float t0 = 0.f, t1 = 0.f, t2 = 0.f, t3 = 0.f;

    for (int s16 = 0; s16 < 8; ++s16) {
        #pragma unroll
        for (int k = 0; k < 16; ++k) {
            const int s = s16 * 16 + k;
            uint2 pv = pq[k];
            float c0 = __builtin_fmaf(bf2f((ushort)(pv.x & 0xffffu)), SC, bias0);
            float c1 = __builtin_fmaf(bf2f((ushort)(pv.x >> 16)),     SC, bias1);
            float c2 = __builtin_fmaf(bf2f((ushort)(pv.y & 0xffffu)), SC, bias2);
            float c3 = __builtin_fmaf(bf2f((ushort)(pv.y >> 16)),     SC, bias3);
            if (quad == 3) { c0 = 0.f; c1 = 0.f; c2 = 0.f; c3 = 0.f; }
            pq[k] = *(const uint2*)(pb + ((s + 16) & 127) * HP_N);  // prefetch
            f32x4 cc = {c0, c1, c2, c3};
            f32x4 d = __builtin_amdgcn_mfma_f32_16x16x16f16(aW, hB, cc, 0, 0, 0);
            t0 = tanh_ps(d[0]);
            t1 = tanh_ps(d[1]);
            t2 = tanh_ps(d[2]);
            t3 = tanh_ps(d[3]);
            f16x4 nh;
            nh[0] = (_Float16)t0;
            nh[1] = (_Float16)t1;
            nh[2] = (_Float16)t2;
            nh[3] = (_Float16)t3;
            hB = nh;
        }
    }

    // epilogue: lane holds h[quad*4+r] (f32) for b=col; gather via LDS
    *(float4*)&ho[bloc][quad * 4] = make_float4(t0, t1, t2, t3);
    if (quad == 0) {
        float4 h0 = *(const float4*)&ho[bloc][0];
        float4 h1 = *(const float4*)&ho[bloc][4];
        float4 h2 = *(const float4*)&ho[bloc][8];
        float hv[12] = {h0.x,h0.y,h0.z,h0.w, h1.x,h1.y,h1.z,h1.w,
                        h2.x,h2.y,h2.z,h2.w};
        const float* rv = rev + b * HP_N;
        float rvv[12];
        #pragma unroll
        for (int k2 = 0; k2 < 12; ++k2) rvv[k2] = rv[k2];
        #pragma unroll
        for (int o = 0; o < OUT_N; ++o) {
            const float* fw = fc_w + o * 24;
            float accv = fc_b[o];
            #pragma unroll
            for (int k2 = 0; k2 < 12; ++k2)
                accv += fw[k2] * hv[k2] + fw[12 + k2] * rvv[k2];
            out[b * OUT_N + o] = accv;
        }
    }
}

// ---------------------------------------------------------------------------
extern "C" void kernel_launch(void* const* d_in, const int* in_sizes, int n_in,
                              void* d_out, int out_size, void* d_ws, size_t ws_size,
                              hipStream_t stream) {
    const int*   x      = (const int*)  d_in[0];
    const float* emb    = (const float*)d_in[1];
    const float* w_ih_f = (const float*)d_in[2];
    const float* w_hh_f = (const float*)d_in[3];
    const float* b_ih_f = (const float*)d_in[4];
    const float* b_hh_f = (const float*)d_in[5];
    const float* w_ih_r = (const float*)d_in[6];
    const float* b_ih_r = (const float*)d_in[8];
    const float* b_hh_r = (const float*)d_in[9];
    const float* fc_w   = (const float*)d_in[10];
    const float* fc_b   = (const float*)d_in[11];
    float* out = (float*)d_out;

    ushort* preB = (ushort*)d_ws;                              // 8 MB
    float*  rev  = (float*)((char*)d_ws + 8388608);            // 128 KB
    ushort* embB = (ushort*)((char*)d_ws + 8519680);           // 128 KB (f16)
    ushort* wP   = (ushort*)((char*)d_ws + 8650752);           // 32 KB  (f16)

    k_prep<<<64,    256, 0, stream>>>(emb, w_ih_f, w_ih_r, embB, wP);
    k_pre <<<B_N/4, 256, 0, stream>>>(x, embB, wP, b_ih_r, b_hh_r, preB, rev);
    k_rnn <<<B_N/64,256, 0, stream>>>(preB, rev, w_hh_f, b_ih_f, b_hh_f, fc_w, fc_b, out);
}